// Round 2
// baseline (762.623 us; speedup 1.0000x reference)
//
#include <hip/hip_runtime.h>

#define NN 50000
#define DIN 128
#define DH  128
#define DOUT 40
#define BN_EPS 1e-5f

__device__ __forceinline__ void atomAddF(float* p, float v) {
  unsafeAtomicAdd(p, v);   // native global_atomic_add_f32 on gfx950
}

// 1. int in-degree histogram over dst (self-loop folded in later)
__global__ void k_deg(const int* __restrict__ dst, int* __restrict__ deg, int E) {
  int e = blockIdx.x * blockDim.x + threadIdx.x;
  if (e < E) atomicAdd(&deg[dst[e]], 1);
}

// 2. single-block exclusive scan of deg -> off, cursor copy, dinv = rsqrt(deg+1)
__global__ __launch_bounds__(1024) void k_scan(const int* __restrict__ deg,
                                               int* __restrict__ off,
                                               int* __restrict__ cur,
                                               float* __restrict__ dinv) {
  __shared__ int s[1024];
  int t = threadIdx.x;
  const int CH = (NN + 1023) / 1024;  // 49
  int base = t * CH;
  int sum = 0;
  for (int i = 0; i < CH; ++i) { int idx = base + i; if (idx < NN) sum += deg[idx]; }
  s[t] = sum;
  __syncthreads();
  for (int o = 1; o < 1024; o <<= 1) {   // Hillis-Steele inclusive scan
    int v = (t >= o) ? s[t - o] : 0;
    __syncthreads();
    s[t] += v;
    __syncthreads();
  }
  int run = s[t] - sum;                  // exclusive base for this chunk
  for (int i = 0; i < CH; ++i) {
    int idx = base + i; if (idx >= NN) break;
    int d = deg[idx];
    off[idx] = run; cur[idx] = run; run += d;
    dinv[idx] = rsqrtf((float)d + 1.0f);
  }
}

// 3. CSR fill: group src indices by dst
__global__ void k_fill(const int* __restrict__ src, const int* __restrict__ dst,
                       int* __restrict__ cur, int* __restrict__ csr, int E) {
  int e = blockIdx.x * blockDim.x + threadIdx.x;
  if (e >= E) return;
  int pos = atomicAdd(&cur[dst[e]], 1);
  csr[pos] = src[e];
}

// 4. Y1[i][j] = dinv[i] * sum_k X[i][k] * W1[k][j]
__global__ void k_gemm1(const float* __restrict__ X, const float* __restrict__ W,
                        const float* __restrict__ dinv, float* __restrict__ Y) {
  int gid = blockIdx.x * 256 + threadIdx.x;
  if (gid >= NN * DH) return;
  int row = gid >> 7, col = gid & 127;
  const float4* X4 = (const float4*)(X + (size_t)row * DIN);
  float sum = 0.f;
#pragma unroll 8
  for (int k4 = 0; k4 < DIN / 4; ++k4) {
    float4 xv = X4[k4];
    int k = k4 * 4;
    sum += xv.x * W[(k + 0) * DH + col];
    sum += xv.y * W[(k + 1) * DH + col];
    sum += xv.z * W[(k + 2) * DH + col];
    sum += xv.w * W[(k + 3) * DH + col];
  }
  Y[gid] = sum * dinv[row];
}

// 5. pull-mode aggregation layer1 + finalize + fused BN column stats.
//    wave per node-quad: Z[n] = dinv[n]*(sum_{s in N(n)} Y1[s] + Y1[n]) + b1
__global__ void k_pull1(const int* __restrict__ off, const int* __restrict__ deg,
                        const int* __restrict__ csr, const float* __restrict__ Y1,
                        const float* __restrict__ dinv, const float* __restrict__ b1,
                        float* __restrict__ Z, float* __restrict__ colsum,
                        float* __restrict__ colsumsq) {
  __shared__ float s_sum[4][128], s_sq[4][128];
  int t = threadIdx.x, lane = t & 63, wid = t >> 6;
  const float2* Y = (const float2*)Y1;
  float bx = b1[2 * lane], by = b1[2 * lane + 1];
  float sx = 0.f, sy = 0.f, qx = 0.f, qy = 0.f;
  int n0 = blockIdx.x * 16 + wid * 4;
  for (int u = 0; u < 4; ++u) {
    int n = n0 + u;                      // NN = 50000 = 3125*16, no tail
    float2 acc = Y[(size_t)n * 64 + lane];   // self loop
    int o = off[n], dg = deg[n];
    for (int k = 0; k < dg; ++k) {
      int sN = csr[o + k];
      float2 y = Y[(size_t)sN * 64 + lane];  // coalesced 512B row read
      acc.x += y.x; acc.y += y.y;
    }
    float dn = dinv[n];
    float zx = fmaf(dn, acc.x, bx);
    float zy = fmaf(dn, acc.y, by);
    ((float2*)Z)[(size_t)n * 64 + lane] = make_float2(zx, zy);
    sx += zx; sy += zy; qx += zx * zx; qy += zy * zy;
  }
  s_sum[wid][2 * lane] = sx; s_sum[wid][2 * lane + 1] = sy;
  s_sq[wid][2 * lane]  = qx; s_sq[wid][2 * lane + 1]  = qy;
  __syncthreads();
  if (t < 128) {
    atomAddF(&colsum[t],   s_sum[0][t] + s_sum[1][t] + s_sum[2][t] + s_sum[3][t]);
    atomAddF(&colsumsq[t], s_sq[0][t] + s_sq[1][t] + s_sq[2][t] + s_sq[3][t]);
  }
}

// 6. BN scale/shift from raw moments (biased var, as torch BN)
__global__ void k_bn(const float* __restrict__ colsum, const float* __restrict__ colsumsq,
                     const float* __restrict__ gamma, const float* __restrict__ beta,
                     float* __restrict__ scale, float* __restrict__ shift) {
  int j = threadIdx.x;
  float mean = colsum[j] * (1.0f / NN);
  float var  = colsumsq[j] * (1.0f / NN) - mean * mean;
  float sc = gamma[j] * rsqrtf(var + BN_EPS);
  scale[j] = sc;
  shift[j] = beta[j] - mean * sc;
}

// 7. x2 = relu(Z*scale+shift); Y2[i][j] = dinv[i]*sum_k x2[k]*W2[k][j]
__global__ void k_gemm2(const float* __restrict__ Z, const float* __restrict__ W2,
                        const float* __restrict__ scale, const float* __restrict__ shift,
                        const float* __restrict__ dinv, float* __restrict__ Y2) {
  __shared__ float x2[DH];
  int i = blockIdx.x;
  int t = threadIdx.x;  // 64 threads
  size_t base = (size_t)i * DH;
  float z0 = Z[base + t]      * scale[t]      + shift[t];
  float z1 = Z[base + t + 64] * scale[t + 64] + shift[t + 64];
  x2[t]      = fmaxf(z0, 0.f);
  x2[t + 64] = fmaxf(z1, 0.f);
  __syncthreads();
  if (t < DOUT) {
    float sum = 0.f;
#pragma unroll 8
    for (int k = 0; k < DH; ++k) sum += x2[k] * W2[k * DOUT + t];
    Y2[(size_t)i * DOUT + t] = sum * dinv[i];
  }
}

// 8. pull-mode aggregation layer2, writes final output directly
__global__ void k_pull2(const int* __restrict__ off, const int* __restrict__ deg,
                        const int* __restrict__ csr, const float* __restrict__ Y2,
                        const float* __restrict__ dinv, const float* __restrict__ b2,
                        float* __restrict__ out) {
  int t = threadIdx.x, lane = t & 63, wid = t >> 6;
  if (lane >= DOUT) return;
  float bv = b2[lane];
  int n0 = blockIdx.x * 16 + wid * 4;
  for (int u = 0; u < 4; ++u) {
    int n = n0 + u;
    float acc = Y2[(size_t)n * DOUT + lane];  // self loop
    int o = off[n], dg = deg[n];
    for (int k = 0; k < dg; ++k) {
      int sN = csr[o + k];
      acc += Y2[(size_t)sN * DOUT + lane];
    }
    out[(size_t)n * DOUT + lane] = fmaf(dinv[n], acc, bv);
  }
}

extern "C" void kernel_launch(void* const* d_in, const int* in_sizes, int n_in,
                              void* d_out, int out_size, void* d_ws, size_t ws_size,
                              hipStream_t stream) {
  const float* X     = (const float*)d_in[0];
  const float* W1    = (const float*)d_in[1];
  const float* b1    = (const float*)d_in[2];
  const float* gamma = (const float*)d_in[3];
  const float* beta  = (const float*)d_in[4];
  const float* W2    = (const float*)d_in[5];
  const float* b2    = (const float*)d_in[6];
  const int*   edges = (const int*)d_in[7];
  int E = in_sizes[7] / 2;
  const int* src = edges;
  const int* dst = edges + E;

  int E4 = (E + 3) & ~3;                     // keep float region 16B-aligned
  int* i_deg = (int*)d_ws;                   // NN (int)
  int* i_off = i_deg + 50048;
  int* i_cur = i_off + 50048;
  int* i_csr = i_cur + 50048;                // E
  float* f_dinv = (float*)(i_csr + E4);      // NN
  float* f_Y1   = f_dinv + 50048;            // NN*DH ; reused as Y2 after pull1
  float* f_Z    = f_Y1 + (size_t)NN * DH;    // NN*DH
  float* f_st   = f_Z + (size_t)NN * DH;     // colsum|colsumsq|scale|shift (4*128)
  float* f_Y2   = f_Y1;                      // alias: Y1 dead after k_pull1

  hipMemsetAsync(i_deg, 0, 50000 * sizeof(int), stream);
  hipMemsetAsync(f_st, 0, 256 * sizeof(float), stream);

  k_deg <<<(E + 255) / 256, 256, 0, stream>>>(dst, i_deg, E);
  k_scan<<<1, 1024, 0, stream>>>(i_deg, i_off, i_cur, f_dinv);
  k_fill<<<(E + 255) / 256, 256, 0, stream>>>(src, dst, i_cur, i_csr, E);
  k_gemm1<<<(NN * DH) / 256, 256, 0, stream>>>(X, W1, f_dinv, f_Y1);
  k_pull1<<<NN / 16, 256, 0, stream>>>(i_off, i_deg, i_csr, f_Y1, f_dinv, b1,
                                       f_Z, f_st, f_st + 128);
  k_bn<<<1, 128, 0, stream>>>(f_st, f_st + 128, gamma, beta, f_st + 256, f_st + 384);
  k_gemm2<<<NN, 64, 0, stream>>>(f_Z, W2, f_st + 256, f_st + 384, f_dinv, f_Y2);
  k_pull2<<<NN / 16, 256, 0, stream>>>(i_off, i_deg, i_csr, f_Y2, f_dinv, b2,
                                       (float*)d_out);
}

// Round 3
// 613.034 us; speedup vs baseline: 1.2440x; 1.2440x over previous
//
#include <hip/hip_runtime.h>

#define NN 50000
#define DIN 128
#define DH  128
#define DOUT 40
#define BN_EPS 1e-5f

__device__ __forceinline__ void atomAddF(float* p, float v) {
  unsafeAtomicAdd(p, v);   // native global_atomic_add_f32 on gfx950
}

// 1. int in-degree histogram over dst (self-loop folded in later)
__global__ void k_deg(const int* __restrict__ dst, int* __restrict__ deg, int E) {
  int e = blockIdx.x * blockDim.x + threadIdx.x;
  if (e < E) atomicAdd(&deg[dst[e]], 1);
}

// 2. single-block exclusive scan of deg -> off, cursor copy, dinv = rsqrt(deg+1)
__global__ __launch_bounds__(1024) void k_scan(const int* __restrict__ deg,
                                               int* __restrict__ off,
                                               int* __restrict__ cur,
                                               float* __restrict__ dinv) {
  __shared__ int s[1024];
  int t = threadIdx.x;
  const int CH = (NN + 1023) / 1024;  // 49
  int base = t * CH;
  int sum = 0;
  for (int i = 0; i < CH; ++i) { int idx = base + i; if (idx < NN) sum += deg[idx]; }
  s[t] = sum;
  __syncthreads();
  for (int o = 1; o < 1024; o <<= 1) {   // Hillis-Steele inclusive scan
    int v = (t >= o) ? s[t - o] : 0;
    __syncthreads();
    s[t] += v;
    __syncthreads();
  }
  int run = s[t] - sum;                  // exclusive base for this chunk
  for (int i = 0; i < CH; ++i) {
    int idx = base + i; if (idx >= NN) break;
    int d = deg[idx];
    off[idx] = run; cur[idx] = run; run += d;
    dinv[idx] = rsqrtf((float)d + 1.0f);
  }
}

// 3. CSR fill: group src indices by dst
__global__ void k_fill(const int* __restrict__ src, const int* __restrict__ dst,
                       int* __restrict__ cur, int* __restrict__ csr, int E) {
  int e = blockIdx.x * blockDim.x + threadIdx.x;
  if (e >= E) return;
  int pos = atomicAdd(&cur[dst[e]], 1);
  csr[pos] = src[e];
}

// 4. Y1[i][j] = dinv[i] * sum_k X[i][k] * W1[k][j]
//    register-blocked: 8 rows x 4 cols per thread, float4 loads both sides.
__global__ __launch_bounds__(256) void k_gemm1(const float* __restrict__ X,
                                               const float* __restrict__ W,
                                               const float* __restrict__ dinv,
                                               float* __restrict__ Y) {
  int t = threadIdx.x;
  int tx = t & 31;          // col quad 0..31 -> c0 = tx*4
  int ty = t >> 5;          // 0..7 -> 8 rows each
  int r0 = blockIdx.x * 64 + ty * 8;
  int c0 = tx * 4;
  const float4* W4 = (const float4*)W;   // quad index = k*32 + tx

  const float* xp[8];
#pragma unroll
  for (int r = 0; r < 8; ++r) {
    int row = r0 + r;
    if (row >= NN) row = NN - 1;         // clamp: safe load, store guarded
    xp[r] = X + (size_t)row * DIN;
  }

  float acc[8][4] = {};
  for (int k = 0; k < DIN; k += 4) {
    float4 w0 = W4[(k + 0) * 32 + tx];
    float4 w1 = W4[(k + 1) * 32 + tx];
    float4 w2 = W4[(k + 2) * 32 + tx];
    float4 w3 = W4[(k + 3) * 32 + tx];
#pragma unroll
    for (int r = 0; r < 8; ++r) {
      float4 xv = *(const float4*)(xp[r] + k);
      acc[r][0] = fmaf(xv.x, w0.x, fmaf(xv.y, w1.x, fmaf(xv.z, w2.x, fmaf(xv.w, w3.x, acc[r][0]))));
      acc[r][1] = fmaf(xv.x, w0.y, fmaf(xv.y, w1.y, fmaf(xv.z, w2.y, fmaf(xv.w, w3.y, acc[r][1]))));
      acc[r][2] = fmaf(xv.x, w0.z, fmaf(xv.y, w1.z, fmaf(xv.z, w2.z, fmaf(xv.w, w3.z, acc[r][2]))));
      acc[r][3] = fmaf(xv.x, w0.w, fmaf(xv.y, w1.w, fmaf(xv.z, w2.w, fmaf(xv.w, w3.w, acc[r][3]))));
    }
  }
#pragma unroll
  for (int r = 0; r < 8; ++r) {
    int row = r0 + r;
    if (row < NN) {
      float dv = dinv[row];
      *(float4*)(Y + (size_t)row * DH + c0) =
          make_float4(acc[r][0] * dv, acc[r][1] * dv, acc[r][2] * dv, acc[r][3] * dv);
    }
  }
}

// 5. pull-mode aggregation layer1 + finalize + fused BN column stats.
//    wave per node-quad: Z[n] = dinv[n]*(sum_{s in N(n)} Y1[s] + Y1[n]) + b1
__global__ void k_pull1(const int* __restrict__ off, const int* __restrict__ deg,
                        const int* __restrict__ csr, const float* __restrict__ Y1,
                        const float* __restrict__ dinv, const float* __restrict__ b1,
                        float* __restrict__ Z, float* __restrict__ colsum,
                        float* __restrict__ colsumsq) {
  __shared__ float s_sum[4][128], s_sq[4][128];
  int t = threadIdx.x, lane = t & 63, wid = t >> 6;
  const float2* Y = (const float2*)Y1;
  float bx = b1[2 * lane], by = b1[2 * lane + 1];
  float sx = 0.f, sy = 0.f, qx = 0.f, qy = 0.f;
  int n0 = blockIdx.x * 16 + wid * 4;
  for (int u = 0; u < 4; ++u) {
    int n = n0 + u;                      // NN = 50000 = 3125*16, no tail
    float2 acc = Y[(size_t)n * 64 + lane];   // self loop
    int o = off[n], dg = deg[n];
    for (int k = 0; k < dg; ++k) {
      int sN = csr[o + k];
      float2 y = Y[(size_t)sN * 64 + lane];  // coalesced 512B row read
      acc.x += y.x; acc.y += y.y;
    }
    float dn = dinv[n];
    float zx = fmaf(dn, acc.x, bx);
    float zy = fmaf(dn, acc.y, by);
    ((float2*)Z)[(size_t)n * 64 + lane] = make_float2(zx, zy);
    sx += zx; sy += zy; qx += zx * zx; qy += zy * zy;
  }
  s_sum[wid][2 * lane] = sx; s_sum[wid][2 * lane + 1] = sy;
  s_sq[wid][2 * lane]  = qx; s_sq[wid][2 * lane + 1]  = qy;
  __syncthreads();
  if (t < 128) {
    atomAddF(&colsum[t],   s_sum[0][t] + s_sum[1][t] + s_sum[2][t] + s_sum[3][t]);
    atomAddF(&colsumsq[t], s_sq[0][t] + s_sq[1][t] + s_sq[2][t] + s_sq[3][t]);
  }
}

// 6. BN scale/shift from raw moments (biased var, as torch BN)
__global__ void k_bn(const float* __restrict__ colsum, const float* __restrict__ colsumsq,
                     const float* __restrict__ gamma, const float* __restrict__ beta,
                     float* __restrict__ scale, float* __restrict__ shift) {
  int j = threadIdx.x;
  float mean = colsum[j] * (1.0f / NN);
  float var  = colsumsq[j] * (1.0f / NN) - mean * mean;
  float sc = gamma[j] * rsqrtf(var + BN_EPS);
  scale[j] = sc;
  shift[j] = beta[j] - mean * sc;
}

// 7. Y2[i][j] = dinv[i] * sum_k relu(Z[i][k]*scale[k]+shift[k]) * W2[k][j]
//    register-blocked 4 rows x 4 cols; BN+ReLU fused into the k-loop.
__global__ __launch_bounds__(256) void k_gemm2(const float* __restrict__ Z,
                                               const float* __restrict__ W2,
                                               const float* __restrict__ scale,
                                               const float* __restrict__ shift,
                                               const float* __restrict__ dinv,
                                               float* __restrict__ Y2) {
  int t = threadIdx.x;
  if (t >= 250) return;
  int tx = t % 10;          // col quad 0..9 -> c0 = tx*4 (DOUT=40)
  int ty = t / 10;          // 0..24 -> 4 rows each -> 100 rows/block
  int r0 = blockIdx.x * 100 + ty * 4;   // grid=500 -> exactly 50000 rows
  int c0 = tx * 4;
  const float4* W4  = (const float4*)W2;     // quad index = k*10 + tx
  const float4* sc4 = (const float4*)scale;
  const float4* sh4 = (const float4*)shift;

  const float* zp[4];
#pragma unroll
  for (int r = 0; r < 4; ++r) zp[r] = Z + (size_t)(r0 + r) * DH;

  float acc[4][4] = {};
  for (int k4 = 0; k4 < DH / 4; ++k4) {
    int k = k4 * 4;
    float4 sc = sc4[k4], sh = sh4[k4];
    float4 w0 = W4[(k + 0) * 10 + tx];
    float4 w1 = W4[(k + 1) * 10 + tx];
    float4 w2 = W4[(k + 2) * 10 + tx];
    float4 w3 = W4[(k + 3) * 10 + tx];
#pragma unroll
    for (int r = 0; r < 4; ++r) {
      float4 zv = *(const float4*)(zp[r] + k);
      float x0 = fmaxf(fmaf(zv.x, sc.x, sh.x), 0.f);
      float x1 = fmaxf(fmaf(zv.y, sc.y, sh.y), 0.f);
      float x2 = fmaxf(fmaf(zv.z, sc.z, sh.z), 0.f);
      float x3 = fmaxf(fmaf(zv.w, sc.w, sh.w), 0.f);
      acc[r][0] = fmaf(x0, w0.x, fmaf(x1, w1.x, fmaf(x2, w2.x, fmaf(x3, w3.x, acc[r][0]))));
      acc[r][1] = fmaf(x0, w0.y, fmaf(x1, w1.y, fmaf(x2, w2.y, fmaf(x3, w3.y, acc[r][1]))));
      acc[r][2] = fmaf(x0, w0.z, fmaf(x1, w1.z, fmaf(x2, w2.z, fmaf(x3, w3.z, acc[r][2]))));
      acc[r][3] = fmaf(x0, w0.w, fmaf(x1, w1.w, fmaf(x2, w2.w, fmaf(x3, w3.w, acc[r][3]))));
    }
  }
#pragma unroll
  for (int r = 0; r < 4; ++r) {
    int row = r0 + r;
    float dv = dinv[row];
    *(float4*)(Y2 + (size_t)row * DOUT + c0) =
        make_float4(acc[r][0] * dv, acc[r][1] * dv, acc[r][2] * dv, acc[r][3] * dv);
  }
}

// 8. pull-mode aggregation layer2, writes final output directly
__global__ void k_pull2(const int* __restrict__ off, const int* __restrict__ deg,
                        const int* __restrict__ csr, const float* __restrict__ Y2,
                        const float* __restrict__ dinv, const float* __restrict__ b2,
                        float* __restrict__ out) {
  int t = threadIdx.x, lane = t & 63, wid = t >> 6;
  if (lane >= DOUT) return;
  float bv = b2[lane];
  int n0 = blockIdx.x * 16 + wid * 4;
  for (int u = 0; u < 4; ++u) {
    int n = n0 + u;
    float acc = Y2[(size_t)n * DOUT + lane];  // self loop
    int o = off[n], dg = deg[n];
    for (int k = 0; k < dg; ++k) {
      int sN = csr[o + k];
      acc += Y2[(size_t)sN * DOUT + lane];
    }
    out[(size_t)n * DOUT + lane] = fmaf(dinv[n], acc, bv);
  }
}

extern "C" void kernel_launch(void* const* d_in, const int* in_sizes, int n_in,
                              void* d_out, int out_size, void* d_ws, size_t ws_size,
                              hipStream_t stream) {
  const float* X     = (const float*)d_in[0];
  const float* W1    = (const float*)d_in[1];
  const float* b1    = (const float*)d_in[2];
  const float* gamma = (const float*)d_in[3];
  const float* beta  = (const float*)d_in[4];
  const float* W2    = (const float*)d_in[5];
  const float* b2    = (const float*)d_in[6];
  const int*   edges = (const int*)d_in[7];
  int E = in_sizes[7] / 2;
  const int* src = edges;
  const int* dst = edges + E;

  int E4 = (E + 3) & ~3;                     // keep float region 16B-aligned
  int* i_deg = (int*)d_ws;                   // NN (int)
  int* i_off = i_deg + 50048;
  int* i_cur = i_off + 50048;
  int* i_csr = i_cur + 50048;                // E
  float* f_dinv = (float*)(i_csr + E4);      // NN
  float* f_Y1   = f_dinv + 50048;            // NN*DH ; reused as Y2 after pull1
  float* f_Z    = f_Y1 + (size_t)NN * DH;    // NN*DH
  float* f_st   = f_Z + (size_t)NN * DH;     // colsum|colsumsq|scale|shift (4*128)
  float* f_Y2   = f_Y1;                      // alias: Y1 dead after k_pull1

  hipMemsetAsync(i_deg, 0, 50000 * sizeof(int), stream);
  hipMemsetAsync(f_st, 0, 256 * sizeof(float), stream);

  k_deg <<<(E + 255) / 256, 256, 0, stream>>>(dst, i_deg, E);
  k_scan<<<1, 1024, 0, stream>>>(i_deg, i_off, i_cur, f_dinv);
  k_fill<<<(E + 255) / 256, 256, 0, stream>>>(src, dst, i_cur, i_csr, E);
  k_gemm1<<<(NN + 63) / 64, 256, 0, stream>>>(X, W1, f_dinv, f_Y1);
  k_pull1<<<NN / 16, 256, 0, stream>>>(i_off, i_deg, i_csr, f_Y1, f_dinv, b1,
                                       f_Z, f_st, f_st + 128);
  k_bn<<<1, 128, 0, stream>>>(f_st, f_st + 128, gamma, beta, f_st + 256, f_st + 384);
  k_gemm2<<<500, 256, 0, stream>>>(f_Z, W2, f_st + 256, f_st + 384, f_dinv, f_Y2);
  k_pull2<<<NN / 16, 256, 0, stream>>>(i_off, i_deg, i_csr, f_Y2, f_dinv, b2,
                                       (float*)d_out);
}

// Round 5
// 432.505 us; speedup vs baseline: 1.7633x; 1.4174x over previous
//
#include <hip/hip_runtime.h>

#define NN 50000
#define DIN 128
#define DH  128
#define DOUT 40
#define BN_EPS 1e-5f

__device__ __forceinline__ void atomAddF(float* p, float v) {
  unsafeAtomicAdd(p, v);   // native global_atomic_add_f32 on gfx950
}

// 1. int in-degree histogram over dst (self-loop folded in later)
__global__ void k_deg(const int* __restrict__ dst, int* __restrict__ deg, int E) {
  int e = blockIdx.x * blockDim.x + threadIdx.x;
  if (e < E) atomicAdd(&deg[dst[e]], 1);
}

// 2. CSR offsets via wave-aggregated atomic counter. Segment ORDER in csr is
//    irrelevant (k_fill assigns slots atomically anyway) and does not affect
//    any floating-point summation order. Replaces the 151µs single-block scan.
__global__ void k_off(const int* __restrict__ deg, int* __restrict__ off,
                      int* __restrict__ cur, float* __restrict__ dinv,
                      int* __restrict__ counter) {
  int i = blockIdx.x * 256 + threadIdx.x;
  int lane = threadIdx.x & 63;
  int d = (i < NN) ? deg[i] : 0;
  int pre = d;
#pragma unroll
  for (int o = 1; o < 64; o <<= 1) {
    int v = __shfl_up(pre, o);
    if (lane >= o) pre += v;
  }
  int tot = __shfl(pre, 63);            // wave total
  int base = 0;
  if (lane == 63) base = atomicAdd(counter, tot);
  base = __shfl(base, 63);
  int o0 = base + pre - d;              // exclusive within wave
  if (i < NN) {
    off[i] = o0; cur[i] = o0;
    dinv[i] = rsqrtf((float)d + 1.0f);
  }
}

// 3. CSR fill: group src indices by dst
__global__ void k_fill(const int* __restrict__ src, const int* __restrict__ dst,
                       int* __restrict__ cur, int* __restrict__ csr, int E) {
  int e = blockIdx.x * blockDim.x + threadIdx.x;
  if (e >= E) return;
  int pos = atomicAdd(&cur[dst[e]], 1);
  csr[pos] = src[e];
}

// 4. Y1[i][j] = dinv[i] * sum_k X[i][k] * W1[k][j]
//    register-blocked: 8 rows x 4 cols per thread, float4 loads both sides.
__global__ __launch_bounds__(256) void k_gemm1(const float* __restrict__ X,
                                               const float* __restrict__ W,
                                               const float* __restrict__ dinv,
                                               float* __restrict__ Y) {
  int t = threadIdx.x;
  int tx = t & 31;          // col quad 0..31 -> c0 = tx*4
  int ty = t >> 5;          // 0..7 -> 8 rows each
  int r0 = blockIdx.x * 64 + ty * 8;
  int c0 = tx * 4;
  const float4* W4 = (const float4*)W;   // quad index = k*32 + tx

  const float* xp[8];
#pragma unroll
  for (int r = 0; r < 8; ++r) {
    int row = r0 + r;
    if (row >= NN) row = NN - 1;         // clamp: safe load, store guarded
    xp[r] = X + (size_t)row * DIN;
  }

  float acc[8][4] = {};
  for (int k = 0; k < DIN; k += 4) {
    float4 w0 = W4[(k + 0) * 32 + tx];
    float4 w1 = W4[(k + 1) * 32 + tx];
    float4 w2 = W4[(k + 2) * 32 + tx];
    float4 w3 = W4[(k + 3) * 32 + tx];
#pragma unroll
    for (int r = 0; r < 8; ++r) {
      float4 xv = *(const float4*)(xp[r] + k);
      acc[r][0] = fmaf(xv.x, w0.x, fmaf(xv.y, w1.x, fmaf(xv.z, w2.x, fmaf(xv.w, w3.x, acc[r][0]))));
      acc[r][1] = fmaf(xv.x, w0.y, fmaf(xv.y, w1.y, fmaf(xv.z, w2.y, fmaf(xv.w, w3.y, acc[r][1]))));
      acc[r][2] = fmaf(xv.x, w0.z, fmaf(xv.y, w1.z, fmaf(xv.z, w2.z, fmaf(xv.w, w3.z, acc[r][2]))));
      acc[r][3] = fmaf(xv.x, w0.w, fmaf(xv.y, w1.w, fmaf(xv.z, w2.w, fmaf(xv.w, w3.w, acc[r][3]))));
    }
  }
#pragma unroll
  for (int r = 0; r < 8; ++r) {
    int row = r0 + r;
    if (row < NN) {
      float dv = dinv[row];
      *(float4*)(Y + (size_t)row * DH + c0) =
          make_float4(acc[r][0] * dv, acc[r][1] * dv, acc[r][2] * dv, acc[r][3] * dv);
    }
  }
}

// 5. pull-mode aggregation layer1 + finalize + fused BN column stats.
//    Wave per node, float2 per lane (exact round-3 summation order: self
//    first, then neighbors sequentially in csr order — numerics-critical).
//    csr indices preloaded 64-wide and broadcast by __shfl so neighbor
//    gathers issue back-to-back (no dependent index-load chain).
__global__ __launch_bounds__(256) void k_pull1(
    const int* __restrict__ off, const int* __restrict__ deg,
    const int* __restrict__ csr, const float* __restrict__ Y1,
    const float* __restrict__ dinv, const float* __restrict__ b1,
    float* __restrict__ Z, float* __restrict__ colsum,
    float* __restrict__ colsumsq) {
  __shared__ float s_sum[4][128], s_sq[4][128];
  int t = threadIdx.x, lane = t & 63, wid = t >> 6;
  const float2* Y = (const float2*)Y1;
  float bx = b1[2 * lane], by = b1[2 * lane + 1];
  float sx = 0.f, sy = 0.f, qx = 0.f, qy = 0.f;
  int n0 = blockIdx.x * 16 + wid * 4;
  for (int u = 0; u < 4; ++u) {
    int n = n0 + u;                      // NN = 3125*16, no tail
    float2 acc = Y[(size_t)n * 64 + lane];   // self loop FIRST (order matters)
    int o = off[n], dg = deg[n];
    for (int base = 0; base < dg; base += 64) {
      int cnt = min(64, dg - base);
      int myidx = (base + lane < dg) ? csr[o + base + lane] : 0;
      for (int k = 0; k < cnt; ++k) {
        int sN = __shfl(myidx, k);
        float2 y = Y[(size_t)sN * 64 + lane];  // coalesced 512B row gather
        acc.x += y.x; acc.y += y.y;
      }
    }
    float dn = dinv[n];
    float zx = fmaf(dn, acc.x, bx);
    float zy = fmaf(dn, acc.y, by);
    ((float2*)Z)[(size_t)n * 64 + lane] = make_float2(zx, zy);
    sx += zx; sy += zy; qx += zx * zx; qy += zy * zy;
  }
  s_sum[wid][2 * lane] = sx; s_sum[wid][2 * lane + 1] = sy;
  s_sq[wid][2 * lane]  = qx; s_sq[wid][2 * lane + 1]  = qy;
  __syncthreads();
  if (t < 128) {
    atomAddF(&colsum[t],   s_sum[0][t] + s_sum[1][t] + s_sum[2][t] + s_sum[3][t]);
    atomAddF(&colsumsq[t], s_sq[0][t] + s_sq[1][t] + s_sq[2][t] + s_sq[3][t]);
  }
}

// 6. BN scale/shift from raw moments (biased var, as torch BN)
__global__ void k_bn(const float* __restrict__ colsum, const float* __restrict__ colsumsq,
                     const float* __restrict__ gamma, const float* __restrict__ beta,
                     float* __restrict__ scale, float* __restrict__ shift) {
  int j = threadIdx.x;
  float mean = colsum[j] * (1.0f / NN);
  float var  = colsumsq[j] * (1.0f / NN) - mean * mean;
  float sc = gamma[j] * rsqrtf(var + BN_EPS);
  scale[j] = sc;
  shift[j] = beta[j] - mean * sc;
}

// 7. Y2[i][j] = dinv[i] * sum_k relu(Z[i][k]*scale[k]+shift[k]) * W2[k][j]
//    register-blocked 4 rows x 4 cols; BN+ReLU fused into the k-loop.
__global__ __launch_bounds__(256) void k_gemm2(const float* __restrict__ Z,
                                               const float* __restrict__ W2,
                                               const float* __restrict__ scale,
                                               const float* __restrict__ shift,
                                               const float* __restrict__ dinv,
                                               float* __restrict__ Y2) {
  int t = threadIdx.x;
  if (t >= 250) return;
  int tx = t % 10;          // col quad 0..9 -> c0 = tx*4 (DOUT=40)
  int ty = t / 10;          // 0..24 -> 4 rows each -> 100 rows/block
  int r0 = blockIdx.x * 100 + ty * 4;   // grid=500 -> exactly 50000 rows
  int c0 = tx * 4;
  const float4* W4  = (const float4*)W2;     // quad index = k*10 + tx
  const float4* sc4 = (const float4*)scale;
  const float4* sh4 = (const float4*)shift;

  const float* zp[4];
#pragma unroll
  for (int r = 0; r < 4; ++r) zp[r] = Z + (size_t)(r0 + r) * DH;

  float acc[4][4] = {};
  for (int k4 = 0; k4 < DH / 4; ++k4) {
    int k = k4 * 4;
    float4 sc = sc4[k4], sh = sh4[k4];
    float4 w0 = W4[(k + 0) * 10 + tx];
    float4 w1 = W4[(k + 1) * 10 + tx];
    float4 w2 = W4[(k + 2) * 10 + tx];
    float4 w3 = W4[(k + 3) * 10 + tx];
#pragma unroll
    for (int r = 0; r < 4; ++r) {
      float4 zv = *(const float4*)(zp[r] + k);
      float x0 = fmaxf(fmaf(zv.x, sc.x, sh.x), 0.f);
      float x1 = fmaxf(fmaf(zv.y, sc.y, sh.y), 0.f);
      float x2 = fmaxf(fmaf(zv.z, sc.z, sh.z), 0.f);
      float x3 = fmaxf(fmaf(zv.w, sc.w, sh.w), 0.f);
      acc[r][0] = fmaf(x0, w0.x, fmaf(x1, w1.x, fmaf(x2, w2.x, fmaf(x3, w3.x, acc[r][0]))));
      acc[r][1] = fmaf(x0, w0.y, fmaf(x1, w1.y, fmaf(x2, w2.y, fmaf(x3, w3.y, acc[r][1]))));
      acc[r][2] = fmaf(x0, w0.z, fmaf(x1, w1.z, fmaf(x2, w2.z, fmaf(x3, w3.z, acc[r][2]))));
      acc[r][3] = fmaf(x0, w0.w, fmaf(x1, w1.w, fmaf(x2, w2.w, fmaf(x3, w3.w, acc[r][3]))));
    }
  }
#pragma unroll
  for (int r = 0; r < 4; ++r) {
    int row = r0 + r;
    float dv = dinv[row];
    *(float4*)(Y2 + (size_t)row * DOUT + c0) =
        make_float4(acc[r][0] * dv, acc[r][1] * dv, acc[r][2] * dv, acc[r][3] * dv);
  }
}

// 8. pull-mode aggregation layer2 with csr shfl-broadcast; writes d_out.
//    Summation order identical to round 3 (self first, neighbors in csr order).
__global__ __launch_bounds__(256) void k_pull2(
    const int* __restrict__ off, const int* __restrict__ deg,
    const int* __restrict__ csr, const float* __restrict__ Y2,
    const float* __restrict__ dinv, const float* __restrict__ b2,
    float* __restrict__ out) {
  int t = threadIdx.x, lane = t & 63, wid = t >> 6;
  bool act = lane < DOUT;
  float bv = act ? b2[lane] : 0.f;
  int n0 = blockIdx.x * 16 + wid * 4;
  for (int u = 0; u < 4; ++u) {
    int n = n0 + u;
    float acc = act ? Y2[(size_t)n * DOUT + lane] : 0.f;   // self loop
    int o = off[n], dg = deg[n];
    for (int base = 0; base < dg; base += 64) {
      int cnt = min(64, dg - base);
      int myidx = (base + lane < dg) ? csr[o + base + lane] : 0;
      for (int k = 0; k < cnt; ++k) {
        int sN = __shfl(myidx, k);
        if (act) acc += Y2[(size_t)sN * DOUT + lane];
      }
    }
    if (act) out[(size_t)n * DOUT + lane] = fmaf(dinv[n], acc, bv);
  }
}

extern "C" void kernel_launch(void* const* d_in, const int* in_sizes, int n_in,
                              void* d_out, int out_size, void* d_ws, size_t ws_size,
                              hipStream_t stream) {
  const float* X     = (const float*)d_in[0];
  const float* W1    = (const float*)d_in[1];
  const float* b1    = (const float*)d_in[2];
  const float* gamma = (const float*)d_in[3];
  const float* beta  = (const float*)d_in[4];
  const float* W2    = (const float*)d_in[5];
  const float* b2    = (const float*)d_in[6];
  const int*   edges = (const int*)d_in[7];
  int E = in_sizes[7] / 2;
  const int* src = edges;
  const int* dst = edges + E;

  int E4 = (E + 3) & ~3;                     // keep float region 16B-aligned
  int* i_deg = (int*)d_ws;                   // NN (int), stride 50048
  int* i_off = i_deg + 50048;
  int* i_cur = i_off + 50048;
  int* i_cnt = i_cur + 50016;                // counter in i_cur's padding
  int* i_csr = i_cur + 50048;                // E
  float* f_dinv = (float*)(i_csr + E4);      // NN
  float* f_Y1   = f_dinv + 50048;            // NN*DH ; reused as Y2 after pull1
  float* f_Z    = f_Y1 + (size_t)NN * DH;    // NN*DH
  float* f_st   = f_Z + (size_t)NN * DH;     // colsum|colsumsq|scale|shift (4*128)
  float* f_Y2   = f_Y1;                      // alias: Y1 dead after k_pull1

  hipMemsetAsync(i_deg, 0, 50000 * sizeof(int), stream);
  hipMemsetAsync(i_cnt, 0, sizeof(int), stream);
  hipMemsetAsync(f_st, 0, 256 * sizeof(float), stream);

  k_deg <<<(E + 255) / 256, 256, 0, stream>>>(dst, i_deg, E);
  k_off <<<(NN + 255) / 256, 256, 0, stream>>>(i_deg, i_off, i_cur, f_dinv, i_cnt);
  k_fill<<<(E + 255) / 256, 256, 0, stream>>>(src, dst, i_cur, i_csr, E);
  k_gemm1<<<(NN + 63) / 64, 256, 0, stream>>>(X, W1, f_dinv, f_Y1);
  k_pull1<<<NN / 16, 256, 0, stream>>>(i_off, i_deg, i_csr, f_Y1, f_dinv, b1,
                                       f_Z, f_st, f_st + 128);
  k_bn<<<1, 128, 0, stream>>>(f_st, f_st + 128, gamma, beta, f_st + 256, f_st + 384);
  k_gemm2<<<500, 256, 0, stream>>>(f_Z, W2, f_st + 256, f_st + 384, f_dinv, f_Y2);
  k_pull2<<<NN / 16, 256, 0, stream>>>(i_off, i_deg, i_csr, f_Y2, f_dinv, b2,
                                       (float*)d_out);
}

// Round 7
// 411.505 us; speedup vs baseline: 1.8533x; 1.0510x over previous
//
#include <hip/hip_runtime.h>

#define NN 50000
#define DIN 128
#define DH  128
#define DOUT 40
#define BN_EPS 1e-5f

__device__ __forceinline__ void atomAddF(float* p, float v) {
  unsafeAtomicAdd(p, v);   // native global_atomic_add_f32 on gfx950
}

// 1. int in-degree histogram over dst (self-loop folded in later)
__global__ void k_deg(const int* __restrict__ dst, int* __restrict__ deg, int E) {
  int e = blockIdx.x * blockDim.x + threadIdx.x;
  if (e < E) atomicAdd(&deg[dst[e]], 1);
}

// 2. CSR offsets via wave-aggregated atomic counter. Segment ORDER in csr is
//    irrelevant (k_fill assigns slots atomically anyway) and does not affect
//    any floating-point summation order. Replaces the 151µs single-block scan.
__global__ void k_off(const int* __restrict__ deg, int* __restrict__ off,
                      int* __restrict__ cur, float* __restrict__ dinv,
                      int* __restrict__ counter) {
  int i = blockIdx.x * 256 + threadIdx.x;
  int lane = threadIdx.x & 63;
  int d = (i < NN) ? deg[i] : 0;
  int pre = d;
#pragma unroll
  for (int o = 1; o < 64; o <<= 1) {
    int v = __shfl_up(pre, o);
    if (lane >= o) pre += v;
  }
  int tot = __shfl(pre, 63);            // wave total
  int base = 0;
  if (lane == 63) base = atomicAdd(counter, tot);
  base = __shfl(base, 63);
  int o0 = base + pre - d;              // exclusive within wave
  if (i < NN) {
    off[i] = o0; cur[i] = o0;
    dinv[i] = rsqrtf((float)d + 1.0f);
  }
}

// 3. CSR fill: group src indices by dst
__global__ void k_fill(const int* __restrict__ src, const int* __restrict__ dst,
                       int* __restrict__ cur, int* __restrict__ csr, int E) {
  int e = blockIdx.x * blockDim.x + threadIdx.x;
  if (e >= E) return;
  int pos = atomicAdd(&cur[dst[e]], 1);
  csr[pos] = src[e];
}

// 4. Y1[i][j] = dinv[i] * sum_k X[i][k] * W1[k][j]
//    register-blocked: 8 rows x 4 cols per thread, float4 loads both sides.
__global__ __launch_bounds__(256) void k_gemm1(const float* __restrict__ X,
                                               const float* __restrict__ W,
                                               const float* __restrict__ dinv,
                                               float* __restrict__ Y) {
  int t = threadIdx.x;
  int tx = t & 31;          // col quad 0..31 -> c0 = tx*4
  int ty = t >> 5;          // 0..7 -> 8 rows each
  int r0 = blockIdx.x * 64 + ty * 8;
  int c0 = tx * 4;
  const float4* W4 = (const float4*)W;   // quad index = k*32 + tx

  const float* xp[8];
#pragma unroll
  for (int r = 0; r < 8; ++r) {
    int row = r0 + r;
    if (row >= NN) row = NN - 1;         // clamp: safe load, store guarded
    xp[r] = X + (size_t)row * DIN;
  }

  float acc[8][4] = {};
  for (int k = 0; k < DIN; k += 4) {
    float4 w0 = W4[(k + 0) * 32 + tx];
    float4 w1 = W4[(k + 1) * 32 + tx];
    float4 w2 = W4[(k + 2) * 32 + tx];
    float4 w3 = W4[(k + 3) * 32 + tx];
#pragma unroll
    for (int r = 0; r < 8; ++r) {
      float4 xv = *(const float4*)(xp[r] + k);
      acc[r][0] = fmaf(xv.x, w0.x, fmaf(xv.y, w1.x, fmaf(xv.z, w2.x, fmaf(xv.w, w3.x, acc[r][0]))));
      acc[r][1] = fmaf(xv.x, w0.y, fmaf(xv.y, w1.y, fmaf(xv.z, w2.y, fmaf(xv.w, w3.y, acc[r][1]))));
      acc[r][2] = fmaf(xv.x, w0.z, fmaf(xv.y, w1.z, fmaf(xv.z, w2.z, fmaf(xv.w, w3.z, acc[r][2]))));
      acc[r][3] = fmaf(xv.x, w0.w, fmaf(xv.y, w1.w, fmaf(xv.z, w2.w, fmaf(xv.w, w3.w, acc[r][3]))));
    }
  }
#pragma unroll
  for (int r = 0; r < 8; ++r) {
    int row = r0 + r;
    if (row < NN) {
      float dv = dinv[row];
      *(float4*)(Y + (size_t)row * DH + c0) =
          make_float4(acc[r][0] * dv, acc[r][1] * dv, acc[r][2] * dv, acc[r][3] * dv);
    }
  }
}

// 5. pull-mode aggregation layer1 + finalize + fused BN column stats.
//    Wave per node, float2 per lane. Summation order IDENTICAL to round 3
//    (self first, then neighbors sequentially in csr order — numerics-
//    critical). Neighbors processed in groups of 8: 8 independent shfl
//    broadcasts + 8 independent row loads issued back-to-back (8 gathers in
//    flight per wave), then added strictly in k order. Pure scheduling change.
__global__ __launch_bounds__(256) void k_pull1(
    const int* __restrict__ off, const int* __restrict__ deg,
    const int* __restrict__ csr, const float* __restrict__ Y1,
    const float* __restrict__ dinv, const float* __restrict__ b1,
    float* __restrict__ Z, float* __restrict__ colsum,
    float* __restrict__ colsumsq) {
  __shared__ float s_sum[4][128], s_sq[4][128];
  int t = threadIdx.x, lane = t & 63, wid = t >> 6;
  const float2* Y = (const float2*)Y1;
  float bx = b1[2 * lane], by = b1[2 * lane + 1];
  float sx = 0.f, sy = 0.f, qx = 0.f, qy = 0.f;
  int n0 = blockIdx.x * 16 + wid * 4;
  for (int u = 0; u < 4; ++u) {
    int n = n0 + u;                      // NN = 3125*16, no tail
    float2 acc = Y[(size_t)n * 64 + lane];   // self loop FIRST (order matters)
    int o = off[n], dg = deg[n];
    for (int base = 0; base < dg; base += 64) {
      int cnt = min(64, dg - base);
      int myidx = (base + lane < dg) ? csr[o + base + lane] : 0;
      int k = 0;
      for (; k + 8 <= cnt; k += 8) {
        int i0 = __shfl(myidx, k + 0), i1 = __shfl(myidx, k + 1);
        int i2 = __shfl(myidx, k + 2), i3 = __shfl(myidx, k + 3);
        int i4 = __shfl(myidx, k + 4), i5 = __shfl(myidx, k + 5);
        int i6 = __shfl(myidx, k + 6), i7 = __shfl(myidx, k + 7);
        float2 y0 = Y[(size_t)i0 * 64 + lane];
        float2 y1 = Y[(size_t)i1 * 64 + lane];
        float2 y2 = Y[(size_t)i2 * 64 + lane];
        float2 y3 = Y[(size_t)i3 * 64 + lane];
        float2 y4 = Y[(size_t)i4 * 64 + lane];
        float2 y5 = Y[(size_t)i5 * 64 + lane];
        float2 y6 = Y[(size_t)i6 * 64 + lane];
        float2 y7 = Y[(size_t)i7 * 64 + lane];
        acc.x += y0.x; acc.y += y0.y;    // adds strictly in k order
        acc.x += y1.x; acc.y += y1.y;
        acc.x += y2.x; acc.y += y2.y;
        acc.x += y3.x; acc.y += y3.y;
        acc.x += y4.x; acc.y += y4.y;
        acc.x += y5.x; acc.y += y5.y;
        acc.x += y6.x; acc.y += y6.y;
        acc.x += y7.x; acc.y += y7.y;
      }
      for (; k < cnt; ++k) {
        int sN = __shfl(myidx, k);
        float2 y = Y[(size_t)sN * 64 + lane];
        acc.x += y.x; acc.y += y.y;
      }
    }
    float dn = dinv[n];
    float zx = fmaf(dn, acc.x, bx);
    float zy = fmaf(dn, acc.y, by);
    ((float2*)Z)[(size_t)n * 64 + lane] = make_float2(zx, zy);
    sx += zx; sy += zy; qx += zx * zx; qy += zy * zy;
  }
  s_sum[wid][2 * lane] = sx; s_sum[wid][2 * lane + 1] = sy;
  s_sq[wid][2 * lane]  = qx; s_sq[wid][2 * lane + 1]  = qy;
  __syncthreads();
  if (t < 128) {
    atomAddF(&colsum[t],   s_sum[0][t] + s_sum[1][t] + s_sum[2][t] + s_sum[3][t]);
    atomAddF(&colsumsq[t], s_sq[0][t] + s_sq[1][t] + s_sq[2][t] + s_sq[3][t]);
  }
}

// 6. BN scale/shift from raw moments (biased var, as torch BN)
__global__ void k_bn(const float* __restrict__ colsum, const float* __restrict__ colsumsq,
                     const float* __restrict__ gamma, const float* __restrict__ beta,
                     float* __restrict__ scale, float* __restrict__ shift) {
  int j = threadIdx.x;
  float mean = colsum[j] * (1.0f / NN);
  float var  = colsumsq[j] * (1.0f / NN) - mean * mean;
  float sc = gamma[j] * rsqrtf(var + BN_EPS);
  scale[j] = sc;
  shift[j] = beta[j] - mean * sc;
}

// 7. Y2[i][j] = dinv[i] * sum_k relu(Z[i][k]*scale[k]+shift[k]) * W2[k][j]
//    register-blocked 4 rows x 4 cols; BN+ReLU fused into the k-loop.
__global__ __launch_bounds__(256) void k_gemm2(const float* __restrict__ Z,
                                               const float* __restrict__ W2,
                                               const float* __restrict__ scale,
                                               const float* __restrict__ shift,
                                               const float* __restrict__ dinv,
                                               float* __restrict__ Y2) {
  int t = threadIdx.x;
  if (t >= 250) return;
  int tx = t % 10;          // col quad 0..9 -> c0 = tx*4 (DOUT=40)
  int ty = t / 10;          // 0..24 -> 4 rows each -> 100 rows/block
  int r0 = blockIdx.x * 100 + ty * 4;   // grid=500 -> exactly 50000 rows
  int c0 = tx * 4;
  const float4* W4  = (const float4*)W2;     // quad index = k*10 + tx
  const float4* sc4 = (const float4*)scale;
  const float4* sh4 = (const float4*)shift;

  const float* zp[4];
#pragma unroll
  for (int r = 0; r < 4; ++r) zp[r] = Z + (size_t)(r0 + r) * DH;

  float acc[4][4] = {};
  for (int k4 = 0; k4 < DH / 4; ++k4) {
    int k = k4 * 4;
    float4 sc = sc4[k4], sh = sh4[k4];
    float4 w0 = W4[(k + 0) * 10 + tx];
    float4 w1 = W4[(k + 1) * 10 + tx];
    float4 w2 = W4[(k + 2) * 10 + tx];
    float4 w3 = W4[(k + 3) * 10 + tx];
#pragma unroll
    for (int r = 0; r < 4; ++r) {
      float4 zv = *(const float4*)(zp[r] + k);
      float x0 = fmaxf(fmaf(zv.x, sc.x, sh.x), 0.f);
      float x1 = fmaxf(fmaf(zv.y, sc.y, sh.y), 0.f);
      float x2 = fmaxf(fmaf(zv.z, sc.z, sh.z), 0.f);
      float x3 = fmaxf(fmaf(zv.w, sc.w, sh.w), 0.f);
      acc[r][0] = fmaf(x0, w0.x, fmaf(x1, w1.x, fmaf(x2, w2.x, fmaf(x3, w3.x, acc[r][0]))));
      acc[r][1] = fmaf(x0, w0.y, fmaf(x1, w1.y, fmaf(x2, w2.y, fmaf(x3, w3.y, acc[r][1]))));
      acc[r][2] = fmaf(x0, w0.z, fmaf(x1, w1.z, fmaf(x2, w2.z, fmaf(x3, w3.z, acc[r][2]))));
      acc[r][3] = fmaf(x0, w0.w, fmaf(x1, w1.w, fmaf(x2, w2.w, fmaf(x3, w3.w, acc[r][3]))));
    }
  }
#pragma unroll
  for (int r = 0; r < 4; ++r) {
    int row = r0 + r;
    float dv = dinv[row];
    *(float4*)(Y2 + (size_t)row * DOUT + c0) =
        make_float4(acc[r][0] * dv, acc[r][1] * dv, acc[r][2] * dv, acc[r][3] * dv);
  }
}

// 8. pull-mode aggregation layer2, 8-deep pipelined gather, same summation
//    order as round 3 (self first, neighbors in csr order); writes d_out.
__global__ __launch_bounds__(256) void k_pull2(
    const int* __restrict__ off, const int* __restrict__ deg,
    const int* __restrict__ csr, const float* __restrict__ Y2,
    const float* __restrict__ dinv, const float* __restrict__ b2,
    float* __restrict__ out) {
  int t = threadIdx.x, lane = t & 63, wid = t >> 6;
  bool act = lane < DOUT;
  float bv = act ? b2[lane] : 0.f;
  int lx = act ? lane : 0;               // safe column for inactive lanes
  int n0 = blockIdx.x * 16 + wid * 4;
  for (int u = 0; u < 4; ++u) {
    int n = n0 + u;
    float acc = act ? Y2[(size_t)n * DOUT + lane] : 0.f;   // self loop
    int o = off[n], dg = deg[n];
    for (int base = 0; base < dg; base += 64) {
      int cnt = min(64, dg - base);
      int myidx = (base + lane < dg) ? csr[o + base + lane] : 0;
      int k = 0;
      for (; k + 8 <= cnt; k += 8) {
        int i0 = __shfl(myidx, k + 0), i1 = __shfl(myidx, k + 1);
        int i2 = __shfl(myidx, k + 2), i3 = __shfl(myidx, k + 3);
        int i4 = __shfl(myidx, k + 4), i5 = __shfl(myidx, k + 5);
        int i6 = __shfl(myidx, k + 6), i7 = __shfl(myidx, k + 7);
        float y0 = Y2[(size_t)i0 * DOUT + lx];
        float y1 = Y2[(size_t)i1 * DOUT + lx];
        float y2 = Y2[(size_t)i2 * DOUT + lx];
        float y3 = Y2[(size_t)i3 * DOUT + lx];
        float y4 = Y2[(size_t)i4 * DOUT + lx];
        float y5 = Y2[(size_t)i5 * DOUT + lx];
        float y6 = Y2[(size_t)i6 * DOUT + lx];
        float y7 = Y2[(size_t)i7 * DOUT + lx];
        acc += y0; acc += y1; acc += y2; acc += y3;   // strict k order
        acc += y4; acc += y5; acc += y6; acc += y7;
      }
      for (; k < cnt; ++k) {
        int sN = __shfl(myidx, k);
        acc += Y2[(size_t)sN * DOUT + lx];
      }
    }
    if (act) out[(size_t)n * DOUT + lane] = fmaf(dinv[n], acc, bv);
  }
}

extern "C" void kernel_launch(void* const* d_in, const int* in_sizes, int n_in,
                              void* d_out, int out_size, void* d_ws, size_t ws_size,
                              hipStream_t stream) {
  const float* X     = (const float*)d_in[0];
  const float* W1    = (const float*)d_in[1];
  const float* b1    = (const float*)d_in[2];
  const float* gamma = (const float*)d_in[3];
  const float* beta  = (const float*)d_in[4];
  const float* W2    = (const float*)d_in[5];
  const float* b2    = (const float*)d_in[6];
  const int*   edges = (const int*)d_in[7];
  int E = in_sizes[7] / 2;
  const int* src = edges;
  const int* dst = edges + E;

  int E4 = (E + 3) & ~3;                     // keep float region 16B-aligned
  int* i_deg = (int*)d_ws;                   // NN (int), stride 50048
  int* i_off = i_deg + 50048;
  int* i_cur = i_off + 50048;
  int* i_cnt = i_cur + 50016;                // counter in i_cur's padding
  int* i_csr = i_cur + 50048;                // E
  float* f_dinv = (float*)(i_csr + E4);      // NN
  float* f_Y1   = f_dinv + 50048;            // NN*DH ; reused as Y2 after pull1
  float* f_Z    = f_Y1 + (size_t)NN * DH;    // NN*DH
  float* f_st   = f_Z + (size_t)NN * DH;     // colsum|colsumsq|scale|shift (4*128)
  float* f_Y2   = f_Y1;                      // alias: Y1 dead after k_pull1

  hipMemsetAsync(i_deg, 0, 50000 * sizeof(int), stream);
  hipMemsetAsync(i_cnt, 0, sizeof(int), stream);
  hipMemsetAsync(f_st, 0, 256 * sizeof(float), stream);

  k_deg <<<(E + 255) / 256, 256, 0, stream>>>(dst, i_deg, E);
  k_off <<<(NN + 255) / 256, 256, 0, stream>>>(i_deg, i_off, i_cur, f_dinv, i_cnt);
  k_fill<<<(E + 255) / 256, 256, 0, stream>>>(src, dst, i_cur, i_csr, E);
  k_gemm1<<<(NN + 63) / 64, 256, 0, stream>>>(X, W1, f_dinv, f_Y1);
  k_pull1<<<NN / 16, 256, 0, stream>>>(i_off, i_deg, i_csr, f_Y1, f_dinv, b1,
                                       f_Z, f_st, f_st + 128);
  k_bn<<<1, 128, 0, stream>>>(f_st, f_st + 128, gamma, beta, f_st + 256, f_st + 384);
  k_gemm2<<<500, 256, 0, stream>>>(f_Z, W2, f_st + 256, f_st + 384, f_dinv, f_Y2);
  k_pull2<<<NN / 16, 256, 0, stream>>>(i_off, i_deg, i_csr, f_Y2, f_dinv, b2,
                                       (float*)d_out);
}